// Round 1
// baseline (268.895 us; speedup 1.0000x reference)
//
#include <hip/hip_runtime.h>
#include <cstdint>

// ---------------------------------------------------------------------------
// H3 block: out = q * S4D( v * Shift(k) ),  q/k/v = W{q,k,v} @ x + b
//   x: (B=8, D=512, L=2048) f32.  Shift = 64-tap depthwise causal conv
//   (kernel = shift_C taps, FFT form collapses since B_fc == 1).
//   S4D: 32 complex modes/channel, chunked scan (T=64) + 64-tap in-chunk conv.
// ---------------------------------------------------------------------------

#define BATCH 8
#define DMODEL 512
#define LSEQ 2048
#define NMODE 32
#define TCH 64
#define NCH 32          // LSEQ / TCH

typedef _Float16 half_t;
typedef __attribute__((ext_vector_type(4))) _Float16 half4v;
typedef __attribute__((ext_vector_type(8))) _Float16 half8v;
typedef __attribute__((ext_vector_type(4))) float floatx4;

// ---------------- convert W (3 x 512x512) fp32 -> f16 ----------------------
__global__ __launch_bounds__(256) void convert_w(
    const float* __restrict__ Wq, const float* __restrict__ Wk,
    const float* __restrict__ Wv, half_t* __restrict__ W16) {
  int i = blockIdx.x * 256 + threadIdx.x;       // 0 .. 3*262144
  const float* src = (i < 262144) ? Wq : ((i < 524288) ? Wk : Wv);
  int j = i & 262143;
  W16[i] = (half_t)src[j];
}

// ---------------- transpose x (B,D,L) f32 -> xT (B,L,D) f16 ----------------
__global__ __launch_bounds__(256) void transpose_x(
    const float* __restrict__ x, half_t* __restrict__ xT) {
  __shared__ float tile[32][33];
  int b = blockIdx.z;
  int d0 = blockIdx.y * 32;
  int l0 = blockIdx.x * 32;
  int tx = threadIdx.x, ty = threadIdx.y;       // 32 x 8
  const float* xp = x + (size_t)b * DMODEL * LSEQ;
#pragma unroll
  for (int k = 0; k < 4; k++)
    tile[ty + 8 * k][tx] = xp[(size_t)(d0 + ty + 8 * k) * LSEQ + l0 + tx];
  __syncthreads();
  half_t* op = xT + (size_t)b * LSEQ * DMODEL;
#pragma unroll
  for (int k = 0; k < 4; k++)
    op[(size_t)(l0 + ty + 8 * k) * DMODEL + d0 + tx] = (half_t)tile[tx][ty + 8 * k];
}

// ---------------- S4D mode constants ---------------------------------------
// mc planes (each 512*32): 0:a  1:b  2:w_re  3:w_im  4:c_re  5:c_im  6:wT_re 7:wT_im
__global__ __launch_bounds__(256) void s4d_setup(
    const float* __restrict__ log_dt, const float* __restrict__ A_real,
    const float* __restrict__ A_imag, const float* __restrict__ C_re,
    const float* __restrict__ C_im, float* __restrict__ mc) {
  int i = blockIdx.x * 256 + threadIdx.x;       // 16384
  int h = i >> 5;
  float dt = expf(log_dt[h]);
  float Ar = -expf(A_real[i]);
  float Ai = A_imag[i];
  float a = dt * Ar, b = dt * Ai;
  float ea = expf(a);
  float wr = ea * cosf(b), wi = ea * sinf(b);
  float Am2 = Ar * Ar + Ai * Ai;
  float zr = wr - 1.0f, zi = wi;                // w - 1
  float qr = (zr * Ar + zi * Ai) / Am2;         // (w-1)/A
  float qi = (zi * Ar - zr * Ai) / Am2;
  float cr = C_re[i] * qr - C_im[i] * qi;
  float ci = C_re[i] * qi + C_im[i] * qr;
  float e64 = expf(64.0f * a);
  float wTr = e64 * cosf(64.0f * b), wTi = e64 * sinf(64.0f * b);
  mc[0 * 16384 + i] = a;   mc[1 * 16384 + i] = b;
  mc[2 * 16384 + i] = wr;  mc[3 * 16384 + i] = wi;
  mc[4 * 16384 + i] = cr;  mc[5 * 16384 + i] = ci;
  mc[6 * 16384 + i] = wTr; mc[7 * 16384 + i] = wTi;
}

// ---------------- GEMM: out[d,n] = sum_h W[d,h] * xT[n,h] + bias[d] --------
// M=512 (d), K=512 (h), N=16384 (b*L+l). Block tile 128x128, BK=32,
// 4 waves (2x2), wave tile 64x64 = 4x4 MFMA 16x16x16 f16 fragments.
#define LDK 40  // padded LDS row (halfs), 80 B = 16B aligned, breaks conflicts

__global__ __launch_bounds__(256) void gemm_qkv(
    const half_t* __restrict__ xT, const half_t* __restrict__ W16all,
    const float* __restrict__ bq, const float* __restrict__ bk,
    const float* __restrict__ bv, float* __restrict__ outq,
    float* __restrict__ outk, float* __restrict__ outv) {
  __shared__ half_t As[128 * LDK];
  __shared__ half_t Bs[128 * LDK];
  int z = blockIdx.z;
  const half_t* W = W16all + (size_t)z * 262144;
  const float* bias = (z == 0) ? bq : ((z == 1) ? bk : bv);
  float* out = (z == 0) ? outq : ((z == 1) ? outk : outv);
  int n0 = blockIdx.x * 128;
  int d0 = blockIdx.y * 128;
  int tid = threadIdx.x;
  int lane = tid & 63, wid = tid >> 6;
  int wr = wid >> 1, wc = wid & 1;              // 2x2 wave grid
  int lrow = lane & 15, lg = lane >> 4;         // frag row / k-group
  int srow = tid >> 2;                          // staging: row within 64
  int skc = (tid & 3) * 8;                      // staging: k col (8 halfs)

  floatx4 acc[4][4];
#pragma unroll
  for (int i = 0; i < 4; i++)
#pragma unroll
    for (int j = 0; j < 4; j++) acc[i][j] = (floatx4){0.f, 0.f, 0.f, 0.f};

  for (int kk = 0; kk < DMODEL; kk += 32) {
#pragma unroll
    for (int p = 0; p < 2; p++) {
      int row = p * 64 + srow;
      half8v av = *(const half8v*)(W + (size_t)(d0 + row) * 512 + kk + skc);
      *(half8v*)(As + row * LDK + skc) = av;
      half8v bvv = *(const half8v*)(xT + (size_t)(n0 + row) * 512 + kk + skc);
      *(half8v*)(Bs + row * LDK + skc) = bvv;
    }
    __syncthreads();
#pragma unroll
    for (int kh = 0; kh < 2; kh++) {
      int ko = kh * 16 + 4 * lg;
      half4v af[4], bf[4];
#pragma unroll
      for (int i = 0; i < 4; i++)
        af[i] = *(const half4v*)(As + (wr * 64 + i * 16 + lrow) * LDK + ko);
#pragma unroll
      for (int j = 0; j < 4; j++)
        bf[j] = *(const half4v*)(Bs + (wc * 64 + j * 16 + lrow) * LDK + ko);
#pragma unroll
      for (int i = 0; i < 4; i++)
#pragma unroll
        for (int j = 0; j < 4; j++)
          acc[i][j] = __builtin_amdgcn_mfma_f32_16x16x16f16(af[i], bf[j],
                                                            acc[i][j], 0, 0, 0);
    }
    __syncthreads();
  }
  // epilogue: D frag: col = lane&15, row = 4*(lane>>4) + reg
  int b = n0 >> 11;                              // whole block inside one batch
#pragma unroll
  for (int i = 0; i < 4; i++) {
    int dbase = d0 + wr * 64 + i * 16 + 4 * lg;
#pragma unroll
    for (int j = 0; j < 4; j++) {
      int n = n0 + wc * 64 + j * 16 + lrow;
      int l = n & 2047;
#pragma unroll
      for (int qi = 0; qi < 4; qi++) {
        int dd = dbase + qi;
        out[((size_t)b * 512 + dd) * 2048 + l] = acc[i][j][qi] + bias[dd];
      }
    }
  }
}

// ---------------- Shift conv (64 taps) + multiply by v ---------------------
__global__ __launch_bounds__(256) void shift_mul(
    const float* __restrict__ kbuf, const float* __restrict__ vbuf,
    const float* __restrict__ shC, const float* __restrict__ shD,
    float* __restrict__ ubuf) {
  __shared__ float kl[320];
  __shared__ float tap[64];
  int bh = blockIdx.y;                           // b*512 + h
  int h = bh & 511;
  int l0 = blockIdx.x * 256;
  int tid = threadIdx.x;
  const float* kp = kbuf + (size_t)bh * 2048;
  if (tid < 64) tap[tid] = shC[h * 64 + tid];
  for (int i = tid; i < 319; i += 256) {
    int l = l0 - 63 + i;
    kl[i] = (l >= 0) ? kp[l] : 0.0f;
  }
  __syncthreads();
  float kc = kl[63 + tid];
  float acc = shD[h] * kc;
#pragma unroll 8
  for (int t = 0; t < 64; t++) acc += tap[t] * kl[63 + tid - t];
  size_t idx = (size_t)bh * 2048 + l0 + tid;
  ubuf[idx] = vbuf[idx] * acc;
}

// ---------------- fused S4D + final q-multiply -----------------------------
// One block per (b,h). Phases:
//  E:  E[r][n] = 2*C*w^{r+1} (re / -im), Ktap[r] = 2*Re(sum_n C w^r)
//  1:  chunk end-states S_j[n] = sum_t w^{63-t} u[j*64+t]
//  2:  scan G_j = w^64 G_{j-1} + S_j  (in-place: SG[j] <- G_{j-1})
//  3:  y[j*64+r] = sum_n(Er*Gre+Ei*Gim) + sum_{t<=r} Ktap[r-t] u[j*64+t]
//      out = q * (y + s4_D * u)
__global__ __launch_bounds__(256) void s4d_main(
    const float* __restrict__ u, const float* qbuf, const float* __restrict__ mc,
    const float* __restrict__ s4D, float* outp) {
  __shared__ float ul[2048];
  __shared__ float SGre[NCH][NMODE], SGim[NCH][NMODE];
  __shared__ float Erl[64][32], Eil[64][32];
  __shared__ float Kt[64];
  int bh = blockIdx.x;
  int h = bh & 511;
  int tid = threadIdx.x;
  const float* up = u + (size_t)bh * 2048;
  for (int i = tid; i < 512; i += 256) ((float4*)ul)[i] = ((const float4*)up)[i];
  if (tid < 64) Kt[tid] = 0.0f;
  __syncthreads();

  // --- phase E: thread -> (r = tid>>2, n = (tid&3)*8 .. +7)
  {
    int r = tid >> 2;
    int nb = (tid & 3) * 8;
    float ksum = 0.f;
#pragma unroll
    for (int i = 0; i < 8; i++) {
      int n = nb + i;
      int hn = h * 32 + n;
      float a = mc[hn], b = mc[16384 + hn];
      float cr = mc[4 * 16384 + hn], ci = mc[5 * 16384 + hn];
      float er = expf(a * (float)r);
      float w0r = er * cosf(b * (float)r), w0i = er * sinf(b * (float)r);  // w^r
      ksum += 2.0f * (cr * w0r - ci * w0i);
      float wr = mc[2 * 16384 + hn], wi = mc[3 * 16384 + hn];
      float w1r = w0r * wr - w0i * wi, w1i = w0r * wi + w0i * wr;          // w^{r+1}
      int ns = n ^ (r & 31);                    // XOR swizzle (bank spread)
      Erl[r][ns] = 2.0f * (cr * w1r - ci * w1i);
      Eil[r][ns] = -2.0f * (cr * w1i + ci * w1r);
    }
    atomicAdd(&Kt[r], ksum);
  }

  // --- phase 1: chunk end-states
  {
    int n = tid & 31, jl = tid >> 5;
    int hn = h * 32 + n;
    float wr = mc[2 * 16384 + hn], wi = mc[3 * 16384 + hn];
#pragma unroll
    for (int c = 0; c < 4; c++) {
      int j = jl + 8 * c;
      const float* ub = ul + j * 64;
      float sr = 0.f, si = 0.f;
#pragma unroll 8
      for (int t = 0; t < 64; t++) {
        float ut = ub[t];
        float nr = wr * sr - wi * si + ut;
        si = wr * si + wi * sr;
        sr = nr;
      }
      SGre[j][n] = sr; SGim[j][n] = si;
    }
  }
  __syncthreads();

  // --- phase 2: 32-step scan over chunks (thread n), SG[j] <- G_{j-1}
  if (tid < 32) {
    int n = tid;
    int hn = h * 32 + n;
    float wTr = mc[6 * 16384 + hn], wTi = mc[7 * 16384 + hn];
    float gr = 0.f, gi = 0.f;
    for (int j = 0; j < 32; j++) {
      float tr = SGre[j][n], ti = SGim[j][n];
      SGre[j][n] = gr; SGim[j][n] = gi;
      float nr = wTr * gr - wTi * gi + tr;
      gi = wTr * gi + wTi * gr + ti;
      gr = nr;
    }
  }
  __syncthreads();

  // --- phase 3: outputs. wave jg handles chunks jg*8 .. jg*8+7
  {
    int r = tid & 63, jg = tid >> 6;
    float er[32], ei[32];
#pragma unroll
    for (int n = 0; n < 32; n++) {
      int ns = n ^ (r & 31);
      er[n] = Erl[r][ns];
      ei[n] = Eil[r][ns];
    }
    float sD = s4D[h];
    const float* qp = qbuf + (size_t)bh * 2048;
    float* op = outp + (size_t)bh * 2048;
#pragma unroll
    for (int c = 0; c < 8; c++) {
      int j = jg * 8 + c;
      float cross = 0.f;
#pragma unroll
      for (int n = 0; n < 32; n++)
        cross += er[n] * SGre[j][n] + ei[n] * SGim[j][n];
      const float* ub = ul + j * 64;
      float conv = 0.f;
      for (int t = 0; t <= r; t++) conv += Kt[r - t] * ub[t];
      float uv = ub[r];
      int l = j * 64 + r;
      op[l] = qp[l] * (cross + conv + sD * uv);
    }
  }
}

// ---------------------------------------------------------------------------
extern "C" void kernel_launch(void* const* d_in, const int* in_sizes, int n_in,
                              void* d_out, int out_size, void* d_ws, size_t ws_size,
                              hipStream_t stream) {
  const float* x      = (const float*)d_in[0];
  const float* Wq     = (const float*)d_in[1];
  const float* bq     = (const float*)d_in[2];
  const float* Wk     = (const float*)d_in[3];
  const float* bk     = (const float*)d_in[4];
  const float* Wv     = (const float*)d_in[5];
  const float* bv     = (const float*)d_in[6];
  const float* shC    = (const float*)d_in[7];
  const float* shD    = (const float*)d_in[8];
  const float* log_dt = (const float*)d_in[9];
  const float* A_real = (const float*)d_in[10];
  const float* A_imag = (const float*)d_in[11];
  const float* C_re   = (const float*)d_in[12];
  const float* C_im   = (const float*)d_in[13];
  const float* s4D    = (const float*)d_in[14];
  float* out = (float*)d_out;
  float* ws  = (float*)d_ws;

  // ws layout (floats): k(8.39M) v(8.39M) u(8.39M) xT16(4.19M fl as halfs)
  //                     W16(393216 fl as halfs) mc(131072)  total ~119.5 MB
  float*  kbuf = ws;
  float*  vbuf = ws + 8388608;
  float*  ubuf = ws + 16777216;
  half_t* xT16 = (half_t*)(ws + 25165824);
  half_t* W16  = (half_t*)(ws + 29360128);
  float*  mc   = ws + 29753344;

  convert_w<<<3072, 256, 0, stream>>>(Wq, Wk, Wv, W16);
  transpose_x<<<dim3(64, 16, 8), dim3(32, 8), 0, stream>>>(x, xT16);
  s4d_setup<<<64, 256, 0, stream>>>(log_dt, A_real, A_imag, C_re, C_im, mc);
  // q -> d_out (re-read by s4d_main and overwritten in place)
  gemm_qkv<<<dim3(128, 4, 3), 256, 0, stream>>>(xT16, W16, bq, bk, bv,
                                                out, kbuf, vbuf);
  shift_mul<<<dim3(8, 4096), 256, 0, stream>>>(kbuf, vbuf, shC, shD, ubuf);
  s4d_main<<<4096, 256, 0, stream>>>(ubuf, out, mc, s4D, out);
}

// Round 2
// 128.336 us; speedup vs baseline: 2.0952x; 2.0952x over previous
//
#include <hip/hip_runtime.h>
#include <cstdint>

// ---------------------------------------------------------------------------
// H3 block: out = q * S4D( v * Shift(k) ),  q/k/v = W{q,k,v} @ x + b
// S4D + Shift reformulated as per-(b,h) chunked MFMA GEMMs (T=64, 32 chunks)
// against per-h precomputed 64x64 f16 tables:
//   T1[r][t] = (t<=r) ? tap[r-t] : 0           (shift, in-chunk)
//   T2[r][t] = (t> r) ? tap[64+r-t] : 0        (shift, prev-chunk carry)
//   V [2n|2n+1][t] = Re|Im(w_n^{63-t})         (chunk end-states)
//   E [r][2n|2n+1] = 2Re|-2Im(C~_n w_n^{r+1})  (cross-chunk output)
//   T [r][t] = (t<=r) ? Kt[r-t] : 0, Kt[d]=2Re(sum_n C~_n w_n^d)  (in-chunk)
// ---------------------------------------------------------------------------

#define BATCH 8
#define DMODEL 512
#define LSEQ 2048

typedef _Float16 half_t;
typedef __attribute__((ext_vector_type(4))) _Float16 half4v;
typedef __attribute__((ext_vector_type(8))) _Float16 half8v;
typedef __attribute__((ext_vector_type(4))) float floatx4;

// ---------------- convert W (3 x 512x512) fp32 -> f16 ----------------------
__global__ __launch_bounds__(256) void convert_w(
    const float* __restrict__ Wq, const float* __restrict__ Wk,
    const float* __restrict__ Wv, half_t* __restrict__ W16) {
  int i = blockIdx.x * 256 + threadIdx.x;
  const float* src = (i < 262144) ? Wq : ((i < 524288) ? Wk : Wv);
  int j = i & 262143;
  W16[i] = (half_t)src[j];
}

// ---------------- transpose x (B,D,L) f32 -> xT (B,L,D) f16 ----------------
__global__ __launch_bounds__(256) void transpose_x(
    const float* __restrict__ x, half_t* __restrict__ xT) {
  __shared__ float tile[32][33];
  int b = blockIdx.z;
  int d0 = blockIdx.y * 32;
  int l0 = blockIdx.x * 32;
  int tx = threadIdx.x, ty = threadIdx.y;       // 32 x 8
  const float* xp = x + (size_t)b * DMODEL * LSEQ;
#pragma unroll
  for (int k = 0; k < 4; k++)
    tile[ty + 8 * k][tx] = xp[(size_t)(d0 + ty + 8 * k) * LSEQ + l0 + tx];
  __syncthreads();
  half_t* op = xT + (size_t)b * LSEQ * DMODEL;
#pragma unroll
  for (int k = 0; k < 4; k++)
    op[(size_t)(l0 + ty + 8 * k) * DMODEL + d0 + tx] = (half_t)tile[tx][ty + 8 * k];
}

// ---------------- S4D mode constants ---------------------------------------
// mc planes (each 512*32): 0:a 1:b 2:w_re 3:w_im 4:c_re 5:c_im 6:wT_re 7:wT_im
__global__ __launch_bounds__(256) void s4d_setup(
    const float* __restrict__ log_dt, const float* __restrict__ A_real,
    const float* __restrict__ A_imag, const float* __restrict__ C_re,
    const float* __restrict__ C_im, float* __restrict__ mc) {
  int i = blockIdx.x * 256 + threadIdx.x;       // 16384
  int h = i >> 5;
  float dt = expf(log_dt[h]);
  float Ar = -expf(A_real[i]);
  float Ai = A_imag[i];
  float a = dt * Ar, b = dt * Ai;
  float ea = expf(a);
  float wr = ea * cosf(b), wi = ea * sinf(b);
  float Am2 = Ar * Ar + Ai * Ai;
  float zr = wr - 1.0f, zi = wi;                // w - 1
  float qr = (zr * Ar + zi * Ai) / Am2;         // (w-1)/A
  float qi = (zi * Ar - zr * Ai) / Am2;
  float cr = C_re[i] * qr - C_im[i] * qi;
  float ci = C_re[i] * qi + C_im[i] * qr;
  float e64 = expf(64.0f * a);
  float wTr = e64 * cosf(64.0f * b), wTi = e64 * sinf(64.0f * b);
  mc[0 * 16384 + i] = a;   mc[1 * 16384 + i] = b;
  mc[2 * 16384 + i] = wr;  mc[3 * 16384 + i] = wi;
  mc[4 * 16384 + i] = cr;  mc[5 * 16384 + i] = ci;
  mc[6 * 16384 + i] = wTr; mc[7 * 16384 + i] = wTi;
}

// ---------------- per-h f16 table builder ----------------------------------
__global__ __launch_bounds__(256) void s4d_tables(
    const float* __restrict__ mc, const float* __restrict__ shC,
    half_t* __restrict__ Vt, half_t* __restrict__ Et, half_t* __restrict__ Tt,
    half_t* __restrict__ T1t, half_t* __restrict__ T2t) {
  __shared__ float Kt[64];
  __shared__ float tapl[64];
  int h = blockIdx.x;
  int tid = threadIdx.x;
  if (tid < 64) { Kt[tid] = 0.f; tapl[tid] = shC[h * 64 + tid]; }
  __syncthreads();
  size_t base = (size_t)h * 4096;
  {
    int r = tid >> 2;
    int nb = (tid & 3) * 8;
    float ksum = 0.f;
#pragma unroll
    for (int i = 0; i < 8; i++) {
      int n = nb + i, hn = h * 32 + n;
      float a = mc[hn], b = mc[16384 + hn];
      float cr = mc[4 * 16384 + hn], ci = mc[5 * 16384 + hn];
      float er = expf(a * (float)r);
      float w0r = er * cosf(b * (float)r), w0i = er * sinf(b * (float)r);
      ksum += 2.f * (cr * w0r - ci * w0i);
      float wr = mc[2 * 16384 + hn], wi = mc[3 * 16384 + hn];
      float w1r = w0r * wr - w0i * wi, w1i = w0r * wi + w0i * wr;
      Et[base + r * 64 + 2 * n]     = (half_t)(2.f * (cr * w1r - ci * w1i));
      Et[base + r * 64 + 2 * n + 1] = (half_t)(-2.f * (cr * w1i + ci * w1r));
      Vt[base + (2 * n) * 64 + (63 - r)]     = (half_t)w0r;
      Vt[base + (2 * n + 1) * 64 + (63 - r)] = (half_t)w0i;
    }
    atomicAdd(&Kt[r], ksum);
  }
  __syncthreads();
#pragma unroll
  for (int e = 0; e < 16; e++) {
    int idx = e * 256 + tid;
    int r = idx >> 6, t = idx & 63;
    int d = r - t;
    Tt[base + idx]  = (d >= 0) ? (half_t)Kt[d] : (half_t)0.f;
    T1t[base + idx] = (d >= 0) ? (half_t)tapl[d] : (half_t)0.f;
    T2t[base + idx] = (d < 0) ? (half_t)tapl[64 + d] : (half_t)0.f;
  }
}

// ---------------- GEMM: out[d,n] = sum_h W[d,h] * xT[n,h] + bias[d] --------
#define LDK 40

__global__ __launch_bounds__(256) void gemm_qkv(
    const half_t* __restrict__ xT, const half_t* __restrict__ W16all,
    const float* __restrict__ bq, const float* __restrict__ bk,
    const float* __restrict__ bv, float* __restrict__ outq,
    half_t* __restrict__ outk, half_t* __restrict__ outv) {
  __shared__ half_t As[128 * LDK];
  __shared__ half_t Bs[128 * LDK];
  int z = blockIdx.z;
  const half_t* W = W16all + (size_t)z * 262144;
  const float* bias = (z == 0) ? bq : ((z == 1) ? bk : bv);
  half_t* outH = (z == 1) ? outk : outv;
  int n0 = blockIdx.x * 128;
  int d0 = blockIdx.y * 128;
  int tid = threadIdx.x;
  int lane = tid & 63, wid = tid >> 6;
  int wr = wid >> 1, wc = wid & 1;
  int lrow = lane & 15, lg = lane >> 4;
  int srow = tid >> 2;
  int skc = (tid & 3) * 8;

  floatx4 acc[4][4];
#pragma unroll
  for (int i = 0; i < 4; i++)
#pragma unroll
    for (int j = 0; j < 4; j++) acc[i][j] = (floatx4){0.f, 0.f, 0.f, 0.f};

  for (int kk = 0; kk < DMODEL; kk += 32) {
#pragma unroll
    for (int p = 0; p < 2; p++) {
      int row = p * 64 + srow;
      half8v av = *(const half8v*)(W + (size_t)(d0 + row) * 512 + kk + skc);
      *(half8v*)(As + row * LDK + skc) = av;
      half8v bvv = *(const half8v*)(xT + (size_t)(n0 + row) * 512 + kk + skc);
      *(half8v*)(Bs + row * LDK + skc) = bvv;
    }
    __syncthreads();
#pragma unroll
    for (int kh = 0; kh < 2; kh++) {
      int ko = kh * 16 + 4 * lg;
      half4v af[4], bf[4];
#pragma unroll
      for (int i = 0; i < 4; i++)
        af[i] = *(const half4v*)(As + (wr * 64 + i * 16 + lrow) * LDK + ko);
#pragma unroll
      for (int j = 0; j < 4; j++)
        bf[j] = *(const half4v*)(Bs + (wc * 64 + j * 16 + lrow) * LDK + ko);
#pragma unroll
      for (int i = 0; i < 4; i++)
#pragma unroll
        for (int j = 0; j < 4; j++)
          acc[i][j] = __builtin_amdgcn_mfma_f32_16x16x16f16(af[i], bf[j],
                                                            acc[i][j], 0, 0, 0);
    }
    __syncthreads();
  }
  int b = n0 >> 11;
#pragma unroll
  for (int i = 0; i < 4; i++) {
    int dbase = d0 + wr * 64 + i * 16 + 4 * lg;
#pragma unroll
    for (int j = 0; j < 4; j++) {
      int n = n0 + wc * 64 + j * 16 + lrow;
      int l = n & 2047;
#pragma unroll
      for (int qi = 0; qi < 4; qi++) {
        int dd = dbase + qi;
        size_t idx = ((size_t)b * 512 + dd) * 2048 + l;
        float val = acc[i][j][qi] + bias[dd];
        if (z == 0) outq[idx] = val;
        else outH[idx] = (half_t)val;
      }
    }
  }
}

// ---------------- fused Shift + S4D + final q-multiply ---------------------
// One block (256 thr) per (b,h). 8 output tiles (16x16) over 4 waves:
// wave w: mi = w&1 (chunk-tile), ri in {w>>1, (w>>1)+2} (r/m-tile).
__global__ __launch_bounds__(256) void s4d_main(
    const half_t* __restrict__ kbuf, const half_t* __restrict__ vbuf,
    const half_t* __restrict__ Vt, const half_t* __restrict__ Et,
    const half_t* __restrict__ Tt, const half_t* __restrict__ T1t,
    const half_t* __restrict__ T2t, const float* __restrict__ mc,
    const float* __restrict__ shD, const float* __restrict__ s4D,
    const float* __restrict__ qbuf, float* __restrict__ outp) {
  __shared__ half_t kl[33 * 72];   // row 0 = zeros, row 1+j = k chunk j
  __shared__ half_t vg[32 * 72];   // v, later reused for Gh (f16 states)
  __shared__ half_t uh[32 * 72];   // u = v * shift(k)
  __shared__ half_t tab0[64 * 72]; // T1 -> E
  __shared__ half_t tab1[64 * 72]; // T2 -> T
  __shared__ half_t tab2[64 * 72]; // V
  __shared__ float SG[32 * 66];
  int bh = blockIdx.x;
  int h = bh & 511;
  int tid = threadIdx.x;
  int lane = tid & 63, wid = tid >> 6;
  int lrow = lane & 15, lg = lane >> 4;
  int mi = wid & 1;
  int ri0 = wid >> 1;

  // ---- stage k, v, tables ----
  if (tid < 9) {
    half8v zz = {(_Float16)0, (_Float16)0, (_Float16)0, (_Float16)0,
                 (_Float16)0, (_Float16)0, (_Float16)0, (_Float16)0};
    *(half8v*)(kl + tid * 8) = zz;
  }
  {
    int sj = tid >> 3, sc = (tid & 7) * 8;
    const half_t* kp = kbuf + (size_t)bh * 2048;
    const half_t* vp = vbuf + (size_t)bh * 2048;
    *(half8v*)(kl + (1 + sj) * 72 + sc) = *(const half8v*)(kp + sj * 64 + sc);
    *(half8v*)(vg + sj * 72 + sc) = *(const half8v*)(vp + sj * 64 + sc);
  }
  {
    size_t tb = (size_t)h * 4096;
#pragma unroll
    for (int e = 0; e < 2; e++) {
      int idx = e * 2048 + tid * 8;
      int r = idx >> 6, c = idx & 63;
      *(half8v*)(tab0 + r * 72 + c) = *(const half8v*)(T1t + tb + idx);
      *(half8v*)(tab1 + r * 72 + c) = *(const half8v*)(T2t + tb + idx);
      *(half8v*)(tab2 + r * 72 + c) = *(const half8v*)(Vt + tb + idx);
    }
  }
  float sDsh = shD[h];
  float sD4 = s4D[h];
  __syncthreads();

  floatx4 acc[2];
  // ---- shift phase: shift[j][r] = k_j @ T1' + k_{j-1} @ T2' ----
  acc[0] = (floatx4){0.f, 0.f, 0.f, 0.f};
  acc[1] = (floatx4){0.f, 0.f, 0.f, 0.f};
#pragma unroll
  for (int ks = 0; ks < 4; ks++) {
    int ko = ks * 16 + 4 * lg;
    half4v a1 = *(const half4v*)(kl + (1 + mi * 16 + lrow) * 72 + ko);
    half4v a2 = *(const half4v*)(kl + (mi * 16 + lrow) * 72 + ko);
#pragma unroll
    for (int tt = 0; tt < 2; tt++) {
      int ri = ri0 + tt * 2;
      half4v b1 = *(const half4v*)(tab0 + (ri * 16 + lrow) * 72 + ko);
      half4v b2 = *(const half4v*)(tab1 + (ri * 16 + lrow) * 72 + ko);
      acc[tt] = __builtin_amdgcn_mfma_f32_16x16x16f16(a1, b1, acc[tt], 0, 0, 0);
      acc[tt] = __builtin_amdgcn_mfma_f32_16x16x16f16(a2, b2, acc[tt], 0, 0, 0);
    }
  }
  // u = v * (shift + shD*k)
#pragma unroll
  for (int tt = 0; tt < 2; tt++) {
    int ri = ri0 + tt * 2;
#pragma unroll
    for (int reg = 0; reg < 4; reg++) {
      int j = mi * 16 + 4 * lg + reg;
      int r = ri * 16 + lrow;
      float kvv = (float)kl[(1 + j) * 72 + r];
      float vvv = (float)vg[j * 72 + r];
      uh[j * 72 + r] = (half_t)(vvv * (acc[tt][reg] + sDsh * kvv));
    }
  }
  __syncthreads();

  // ---- S phase: S[j][m] = u_j @ V' ----
  acc[0] = (floatx4){0.f, 0.f, 0.f, 0.f};
  acc[1] = (floatx4){0.f, 0.f, 0.f, 0.f};
#pragma unroll
  for (int ks = 0; ks < 4; ks++) {
    int ko = ks * 16 + 4 * lg;
    half4v a = *(const half4v*)(uh + (mi * 16 + lrow) * 72 + ko);
#pragma unroll
    for (int tt = 0; tt < 2; tt++) {
      int ri = ri0 + tt * 2;
      half4v b = *(const half4v*)(tab2 + (ri * 16 + lrow) * 72 + ko);
      acc[tt] = __builtin_amdgcn_mfma_f32_16x16x16f16(a, b, acc[tt], 0, 0, 0);
    }
  }
#pragma unroll
  for (int tt = 0; tt < 2; tt++) {
    int ri = ri0 + tt * 2;
#pragma unroll
    for (int reg = 0; reg < 4; reg++) {
      int j = mi * 16 + 4 * lg + reg;
      SG[j * 66 + ri * 16 + lrow] = acc[tt][reg];
    }
  }
  __syncthreads();

  // ---- scan (tid<32) + stage E,T into tab0,tab1 (all threads) ----
  if (tid < 32) {
    int n = tid, hn = h * 32 + n;
    float wTr = mc[6 * 16384 + hn], wTi = mc[7 * 16384 + hn];
    float gr = 0.f, gi = 0.f;
    for (int j = 0; j < 32; j++) {
      float tr = SG[j * 66 + 2 * n], ti = SG[j * 66 + 2 * n + 1];
      SG[j * 66 + 2 * n] = gr; SG[j * 66 + 2 * n + 1] = gi;
      float nr = wTr * gr - wTi * gi + tr;
      gi = wTr * gi + wTi * gr + ti;
      gr = nr;
    }
  }
  {
    size_t tb = (size_t)h * 4096;
#pragma unroll
    for (int e = 0; e < 2; e++) {
      int idx = e * 2048 + tid * 8;
      int r = idx >> 6, c = idx & 63;
      *(half8v*)(tab0 + r * 72 + c) = *(const half8v*)(Et + tb + idx);
      *(half8v*)(tab1 + r * 72 + c) = *(const half8v*)(Tt + tb + idx);
    }
  }
  __syncthreads();

  // ---- convert G (f32, in SG) -> f16 into vg ----
  {
    int j = tid >> 3, m0 = (tid & 7) * 8;
    half8v g;
#pragma unroll
    for (int i = 0; i < 8; i++) g[i] = (half_t)SG[j * 66 + m0 + i];
    *(half8v*)(vg + j * 72 + m0) = g;
  }
  __syncthreads();

  // ---- Y phase: Y[j][r] = G~_j @ E' + u_j @ T' ; out = q*(Y + sD*u) ----
  acc[0] = (floatx4){0.f, 0.f, 0.f, 0.f};
  acc[1] = (floatx4){0.f, 0.f, 0.f, 0.f};
#pragma unroll
  for (int ks = 0; ks < 4; ks++) {
    int ko = ks * 16 + 4 * lg;
    half4v ag = *(const half4v*)(vg + (mi * 16 + lrow) * 72 + ko);
    half4v au = *(const half4v*)(uh + (mi * 16 + lrow) * 72 + ko);
#pragma unroll
    for (int tt = 0; tt < 2; tt++) {
      int ri = ri0 + tt * 2;
      half4v be = *(const half4v*)(tab0 + (ri * 16 + lrow) * 72 + ko);
      half4v bt = *(const half4v*)(tab1 + (ri * 16 + lrow) * 72 + ko);
      acc[tt] = __builtin_amdgcn_mfma_f32_16x16x16f16(ag, be, acc[tt], 0, 0, 0);
      acc[tt] = __builtin_amdgcn_mfma_f32_16x16x16f16(au, bt, acc[tt], 0, 0, 0);
    }
  }
  const float* qp = qbuf + (size_t)bh * 2048;
  float* op = outp + (size_t)bh * 2048;
#pragma unroll
  for (int tt = 0; tt < 2; tt++) {
    int ri = ri0 + tt * 2;
#pragma unroll
    for (int reg = 0; reg < 4; reg++) {
      int j = mi * 16 + 4 * lg + reg;
      int r = ri * 16 + lrow;
      int l = j * 64 + r;
      float y = acc[tt][reg] + sD4 * (float)uh[j * 72 + r];
      op[l] = qp[l] * y;
    }
  }
}

// ---------------------------------------------------------------------------
extern "C" void kernel_launch(void* const* d_in, const int* in_sizes, int n_in,
                              void* d_out, int out_size, void* d_ws, size_t ws_size,
                              hipStream_t stream) {
  const float* x      = (const float*)d_in[0];
  const float* Wq     = (const float*)d_in[1];
  const float* bq     = (const float*)d_in[2];
  const float* Wk     = (const float*)d_in[3];
  const float* bk     = (const float*)d_in[4];
  const float* Wv     = (const float*)d_in[5];
  const float* bv     = (const float*)d_in[6];
  const float* shC    = (const float*)d_in[7];
  const float* shD    = (const float*)d_in[8];
  const float* log_dt = (const float*)d_in[9];
  const float* A_real = (const float*)d_in[10];
  const float* A_imag = (const float*)d_in[11];
  const float* C_re   = (const float*)d_in[12];
  const float* C_im   = (const float*)d_in[13];
  const float* s4D    = (const float*)d_in[14];
  float* out = (float*)d_out;
  half_t* wsh = (half_t*)d_ws;

  // ws layout (halfs): kbuf vbuf xT16 W16 Vt Et Tt T1t T2t | mc (f32)
  half_t* kbuf = wsh;                         // 8388608
  half_t* vbuf = wsh + 8388608;               // 8388608
  half_t* xT16 = wsh + 16777216;              // 8388608
  half_t* W16  = wsh + 25165824;              // 786432
  half_t* Vt   = wsh + 25952256;              // 2097152
  half_t* Et   = wsh + 28049408;              // 2097152
  half_t* Tt   = wsh + 30146560;              // 2097152
  half_t* T1t  = wsh + 32243712;              // 2097152
  half_t* T2t  = wsh + 34340864;              // 2097152
  float*  mc   = (float*)(wsh + 36438016);    // 131072 f32

  convert_w<<<3072, 256, 0, stream>>>(Wq, Wk, Wv, W16);
  transpose_x<<<dim3(64, 16, 8), dim3(32, 8), 0, stream>>>(x, xT16);
  s4d_setup<<<64, 256, 0, stream>>>(log_dt, A_real, A_imag, C_re, C_im, mc);
  s4d_tables<<<512, 256, 0, stream>>>(mc, shC, Vt, Et, Tt, T1t, T2t);
  gemm_qkv<<<dim3(128, 4, 3), 256, 0, stream>>>(xT16, W16, bq, bk, bv,
                                                out, kbuf, vbuf);
  s4d_main<<<4096, 256, 0, stream>>>(kbuf, vbuf, Vt, Et, Tt, T1t, T2t,
                                     mc, shD, s4D, out, out);
}

// Round 3
// 100.980 us; speedup vs baseline: 2.6629x; 1.2709x over previous
//
#include <hip/hip_runtime.h>
#include <cstdint>

// ---------------------------------------------------------------------------
// H3 block: out = q * S4D( v * Shift(k) ),  q/k/v = W{q,k,v} @ x + b
// GEMM: merged M=1536 (Wq|Wk|Wv stacked) x N=16384 x K=512, m97-structure:
//   128x128 tile, BK=64, global_load_lds(16B) with inverse-swizzled source,
//   XOR-swizzled ds_read_b128, mfma_f32_16x16x32_f16, XCD-aware block swizzle.
// S4D + Shift as per-(b,h) chunked MFMA GEMMs (T=64) vs per-h f16 tables.
// ---------------------------------------------------------------------------

#define BATCH 8
#define DMODEL 512
#define LSEQ 2048

typedef _Float16 half_t;
typedef __attribute__((ext_vector_type(4))) _Float16 half4v;
typedef __attribute__((ext_vector_type(8))) _Float16 half8v;
typedef __attribute__((ext_vector_type(4))) float floatx4;

__device__ __forceinline__ void gload_lds16(const half_t* g, half_t* l) {
  __builtin_amdgcn_global_load_lds(
      (const __attribute__((address_space(1))) uint32_t*)g,
      (__attribute__((address_space(3))) uint32_t*)l, 16, 0, 0);
}

// ---------------- convert W (3 x 512x512) fp32 -> f16 ----------------------
__global__ __launch_bounds__(256) void convert_w(
    const float* __restrict__ Wq, const float* __restrict__ Wk,
    const float* __restrict__ Wv, half_t* __restrict__ W16) {
  int i = blockIdx.x * 256 + threadIdx.x;
  const float* src = (i < 262144) ? Wq : ((i < 524288) ? Wk : Wv);
  int j = i & 262143;
  W16[i] = (half_t)src[j];
}

// ---------------- transpose x (B,D,L) f32 -> xT (B,L,D) f16 ----------------
__global__ __launch_bounds__(256) void transpose_x(
    const float* __restrict__ x, half_t* __restrict__ xT) {
  __shared__ float tile[32][33];
  int b = blockIdx.z;
  int d0 = blockIdx.y * 32;
  int l0 = blockIdx.x * 32;
  int tx = threadIdx.x, ty = threadIdx.y;       // 32 x 8
  const float* xp = x + (size_t)b * DMODEL * LSEQ;
#pragma unroll
  for (int k = 0; k < 4; k++)
    tile[ty + 8 * k][tx] = xp[(size_t)(d0 + ty + 8 * k) * LSEQ + l0 + tx];
  __syncthreads();
  half_t* op = xT + (size_t)b * LSEQ * DMODEL;
#pragma unroll
  for (int k = 0; k < 4; k++)
    op[(size_t)(l0 + ty + 8 * k) * DMODEL + d0 + tx] = (half_t)tile[tx][ty + 8 * k];
}

// ---------------- S4D mode constants ---------------------------------------
__global__ __launch_bounds__(256) void s4d_setup(
    const float* __restrict__ log_dt, const float* __restrict__ A_real,
    const float* __restrict__ A_imag, const float* __restrict__ C_re,
    const float* __restrict__ C_im, float* __restrict__ mc) {
  int i = blockIdx.x * 256 + threadIdx.x;       // 16384
  int h = i >> 5;
  float dt = expf(log_dt[h]);
  float Ar = -expf(A_real[i]);
  float Ai = A_imag[i];
  float a = dt * Ar, b = dt * Ai;
  float ea = expf(a);
  float wr = ea * cosf(b), wi = ea * sinf(b);
  float Am2 = Ar * Ar + Ai * Ai;
  float zr = wr - 1.0f, zi = wi;
  float qr = (zr * Ar + zi * Ai) / Am2;
  float qi = (zi * Ar - zr * Ai) / Am2;
  float cr = C_re[i] * qr - C_im[i] * qi;
  float ci = C_re[i] * qi + C_im[i] * qr;
  float e64 = expf(64.0f * a);
  float wTr = e64 * cosf(64.0f * b), wTi = e64 * sinf(64.0f * b);
  mc[0 * 16384 + i] = a;   mc[1 * 16384 + i] = b;
  mc[2 * 16384 + i] = wr;  mc[3 * 16384 + i] = wi;
  mc[4 * 16384 + i] = cr;  mc[5 * 16384 + i] = ci;
  mc[6 * 16384 + i] = wTr; mc[7 * 16384 + i] = wTi;
}

// ---------------- per-h f16 table builder ----------------------------------
__global__ __launch_bounds__(256) void s4d_tables(
    const float* __restrict__ mc, const float* __restrict__ shC,
    half_t* __restrict__ Vt, half_t* __restrict__ Et, half_t* __restrict__ Tt,
    half_t* __restrict__ T1t, half_t* __restrict__ T2t) {
  __shared__ float Kt[64];
  __shared__ float tapl[64];
  int h = blockIdx.x;
  int tid = threadIdx.x;
  if (tid < 64) { Kt[tid] = 0.f; tapl[tid] = shC[h * 64 + tid]; }
  __syncthreads();
  size_t base = (size_t)h * 4096;
  {
    int r = tid >> 2;
    int nb = (tid & 3) * 8;
    float ksum = 0.f;
#pragma unroll
    for (int i = 0; i < 8; i++) {
      int n = nb + i, hn = h * 32 + n;
      float a = mc[hn], b = mc[16384 + hn];
      float cr = mc[4 * 16384 + hn], ci = mc[5 * 16384 + hn];
      float er = expf(a * (float)r);
      float w0r = er * cosf(b * (float)r), w0i = er * sinf(b * (float)r);
      ksum += 2.f * (cr * w0r - ci * w0i);
      float wr = mc[2 * 16384 + hn], wi = mc[3 * 16384 + hn];
      float w1r = w0r * wr - w0i * wi, w1i = w0r * wi + w0i * wr;
      Et[base + r * 64 + 2 * n]     = (half_t)(2.f * (cr * w1r - ci * w1i));
      Et[base + r * 64 + 2 * n + 1] = (half_t)(-2.f * (cr * w1i + ci * w1r));
      Vt[base + (2 * n) * 64 + (63 - r)]     = (half_t)w0r;
      Vt[base + (2 * n + 1) * 64 + (63 - r)] = (half_t)w0i;
    }
    atomicAdd(&Kt[r], ksum);
  }
  __syncthreads();
#pragma unroll
  for (int e = 0; e < 16; e++) {
    int idx = e * 256 + tid;
    int r = idx >> 6, t = idx & 63;
    int d = r - t;
    Tt[base + idx]  = (d >= 0) ? (half_t)Kt[d] : (half_t)0.f;
    T1t[base + idx] = (d >= 0) ? (half_t)tapl[d] : (half_t)0.f;
    T2t[base + idx] = (d < 0) ? (half_t)tapl[64 + d] : (half_t)0.f;
  }
}

// ---------------- merged qkv GEMM (m97 structure) --------------------------
// out[m,n] = sum_h Wstk[m,h]*xT[n,h] + bias, m in [0,1536), n in [0,16384)
__global__ __launch_bounds__(256) void gemm_qkv(
    const half_t* __restrict__ xT, const half_t* __restrict__ Wstk,
    const float* __restrict__ bq, const float* __restrict__ bk,
    const float* __restrict__ bv, half_t* __restrict__ outq,
    half_t* __restrict__ outk, half_t* __restrict__ outv) {
  __shared__ half_t As[128 * 64];   // [row][64] halfs, slots XOR-swizzled
  __shared__ half_t Bs[128 * 64];
  int flat = blockIdx.x;                         // 1536 = 128 nt x 12 mt
  int swz = (flat & 7) * 192 + (flat >> 3);      // XCD chunk swizzle
  int nt = swz / 12, mt = swz - nt * 12;
  int n0 = nt * 128, m0 = mt * 128;
  int tid = threadIdx.x;
  int lane = tid & 63, wid = tid >> 6;
  int wr = wid >> 1, wc = wid & 1;
  int lrow = lane & 15, lg = lane >> 4;
  int rsub = lane >> 3, ssub = lane & 7;
  int gslot = ssub ^ rsub;                       // inverse-swizzled source slot

  floatx4 acc[4][4];
#pragma unroll
  for (int i = 0; i < 4; i++)
#pragma unroll
    for (int j = 0; j < 4; j++) acc[i][j] = (floatx4){0.f, 0.f, 0.f, 0.f};

  const half_t* gA = Wstk + (size_t)(m0 + wid * 32 + rsub) * 512 + gslot * 8;
  const half_t* gB = xT + (size_t)(n0 + wid * 32 + rsub) * 512 + gslot * 8;

  for (int kk = 0; kk < 512; kk += 64) {
    // stage: each wave fills rows [wid*32, wid*32+32) of As and Bs
#pragma unroll
    for (int i = 0; i < 4; i++) {
      int c = wid * 4 + i;                       // 1KB chunk, rows c*8..c*8+7
      gload_lds16(gA + (size_t)i * 8 * 512 + kk, As + c * 512);
      gload_lds16(gB + (size_t)i * 8 * 512 + kk, Bs + c * 512);
    }
    __syncthreads();
#pragma unroll
    for (int h = 0; h < 2; h++) {
      half8v af[4], bf[4];
#pragma unroll
      for (int i = 0; i < 4; i++) {
        int r = wr * 64 + i * 16 + lrow;
        int s = (h * 4 + lg) ^ (r & 7);
        af[i] = *(const half8v*)(As + r * 64 + s * 8);
      }
#pragma unroll
      for (int j = 0; j < 4; j++) {
        int r = wc * 64 + j * 16 + lrow;
        int s = (h * 4 + lg) ^ (r & 7);
        bf[j] = *(const half8v*)(Bs + r * 64 + s * 8);
      }
#pragma unroll
      for (int i = 0; i < 4; i++)
#pragma unroll
        for (int j = 0; j < 4; j++)
          acc[i][j] = __builtin_amdgcn_mfma_f32_16x16x32_f16(af[i], bf[j],
                                                             acc[i][j], 0, 0, 0);
    }
    __syncthreads();
  }
  // epilogue: D frag col = lane&15 (n), row = 4*(lane>>4)+reg (m)
#pragma unroll
  for (int i = 0; i < 4; i++) {
    int dd = m0 + wr * 64 + i * 16 + 4 * lg;
    int z = dd >> 9;
    const float* bias = (z == 0) ? bq : ((z == 1) ? bk : bv);
    half_t* outp = (z == 0) ? outq : ((z == 1) ? outk : outv);
    int d = dd & 511;
#pragma unroll
    for (int j = 0; j < 4; j++) {
      int n = n0 + wc * 64 + j * 16 + lrow;
      int b = n >> 11, l = n & 2047;
#pragma unroll
      for (int reg = 0; reg < 4; reg++)
        outp[((size_t)(b * 512 + d + reg)) * 2048 + l] =
            (half_t)(acc[i][j][reg] + bias[d + reg]);
    }
  }
}

// ---------------- fused Shift + S4D + final q-multiply ---------------------
__global__ __launch_bounds__(256) void s4d_main(
    const half_t* __restrict__ kbuf, const half_t* __restrict__ vbuf,
    const half_t* __restrict__ Vt, const half_t* __restrict__ Et,
    const half_t* __restrict__ Tt, const half_t* __restrict__ T1t,
    const half_t* __restrict__ T2t, const float* __restrict__ mc,
    const float* __restrict__ shD, const float* __restrict__ s4D,
    const half_t* __restrict__ qbuf, float* __restrict__ outp) {
  __shared__ half_t kl[33 * 72];   // row 0 = zeros, row 1+j = k chunk j
  __shared__ half_t vg[32 * 72];   // v, later reused for Gh (f16 states)
  __shared__ half_t uh[32 * 72];   // u = v * shift(k)
  __shared__ half_t tab0[64 * 72]; // T1 -> E
  __shared__ half_t tab1[64 * 72]; // T2 -> T
  __shared__ half_t tab2[64 * 72]; // V
  __shared__ float SG[32 * 66];
  int bh = blockIdx.x;
  int h = bh & 511;
  int tid = threadIdx.x;
  int lane = tid & 63, wid = tid >> 6;
  int lrow = lane & 15, lg = lane >> 4;
  int mi = wid & 1;
  int ri0 = wid >> 1;

  if (tid < 9) {
    half8v zz = {(_Float16)0, (_Float16)0, (_Float16)0, (_Float16)0,
                 (_Float16)0, (_Float16)0, (_Float16)0, (_Float16)0};
    *(half8v*)(kl + tid * 8) = zz;
  }
  {
    int sj = tid >> 3, sc = (tid & 7) * 8;
    const half_t* kp = kbuf + (size_t)bh * 2048;
    const half_t* vp = vbuf + (size_t)bh * 2048;
    *(half8v*)(kl + (1 + sj) * 72 + sc) = *(const half8v*)(kp + sj * 64 + sc);
    *(half8v*)(vg + sj * 72 + sc) = *(const half8v*)(vp + sj * 64 + sc);
  }
  {
    size_t tb = (size_t)h * 4096;
#pragma unroll
    for (int e = 0; e < 2; e++) {
      int idx = e * 2048 + tid * 8;
      int r = idx >> 6, c = idx & 63;
      *(half8v*)(tab0 + r * 72 + c) = *(const half8v*)(T1t + tb + idx);
      *(half8v*)(tab1 + r * 72 + c) = *(const half8v*)(T2t + tb + idx);
      *(half8v*)(tab2 + r * 72 + c) = *(const half8v*)(Vt + tb + idx);
    }
  }
  float sDsh = shD[h];
  float sD4 = s4D[h];
  __syncthreads();

  floatx4 acc[2];
  // ---- shift phase: shift[j][r] = k_j @ T1' + k_{j-1} @ T2' ----
  acc[0] = (floatx4){0.f, 0.f, 0.f, 0.f};
  acc[1] = (floatx4){0.f, 0.f, 0.f, 0.f};
#pragma unroll
  for (int ks = 0; ks < 4; ks++) {
    int ko = ks * 16 + 4 * lg;
    half4v a1 = *(const half4v*)(kl + (1 + mi * 16 + lrow) * 72 + ko);
    half4v a2 = *(const half4v*)(kl + (mi * 16 + lrow) * 72 + ko);
#pragma unroll
    for (int tt = 0; tt < 2; tt++) {
      int ri = ri0 + tt * 2;
      half4v b1 = *(const half4v*)(tab0 + (ri * 16 + lrow) * 72 + ko);
      half4v b2 = *(const half4v*)(tab1 + (ri * 16 + lrow) * 72 + ko);
      acc[tt] = __builtin_amdgcn_mfma_f32_16x16x16f16(a1, b1, acc[tt], 0, 0, 0);
      acc[tt] = __builtin_amdgcn_mfma_f32_16x16x16f16(a2, b2, acc[tt], 0, 0, 0);
    }
  }
#pragma unroll
  for (int tt = 0; tt < 2; tt++) {
    int ri = ri0 + tt * 2;
#pragma unroll
    for (int reg = 0; reg < 4; reg++) {
      int j = mi * 16 + 4 * lg + reg;
      int r = ri * 16 + lrow;
      float kvv = (float)kl[(1 + j) * 72 + r];
      float vvv = (float)vg[j * 72 + r];
      uh[j * 72 + r] = (half_t)(vvv * (acc[tt][reg] + sDsh * kvv));
    }
  }
  __syncthreads();

  // ---- S phase: S[j][m] = u_j @ V' ----
  acc[0] = (floatx4){0.f, 0.f, 0.f, 0.f};
  acc[1] = (floatx4){0.f, 0.f, 0.f, 0.f};
#pragma unroll
  for (int ks = 0; ks < 4; ks++) {
    int ko = ks * 16 + 4 * lg;
    half4v a = *(const half4v*)(uh + (mi * 16 + lrow) * 72 + ko);
#pragma unroll
    for (int tt = 0; tt < 2; tt++) {
      int ri = ri0 + tt * 2;
      half4v b = *(const half4v*)(tab2 + (ri * 16 + lrow) * 72 + ko);
      acc[tt] = __builtin_amdgcn_mfma_f32_16x16x16f16(a, b, acc[tt], 0, 0, 0);
    }
  }
#pragma unroll
  for (int tt = 0; tt < 2; tt++) {
    int ri = ri0 + tt * 2;
#pragma unroll
    for (int reg = 0; reg < 4; reg++) {
      int j = mi * 16 + 4 * lg + reg;
      SG[j * 66 + ri * 16 + lrow] = acc[tt][reg];
    }
  }
  __syncthreads();

  // ---- scan (tid<32) + stage E,T into tab0,tab1 ----
  if (tid < 32) {
    int n = tid, hn = h * 32 + n;
    float wTr = mc[6 * 16384 + hn], wTi = mc[7 * 16384 + hn];
    float gr = 0.f, gi = 0.f;
    for (int j = 0; j < 32; j++) {
      float tr = SG[j * 66 + 2 * n], ti = SG[j * 66 + 2 * n + 1];
      SG[j * 66 + 2 * n] = gr; SG[j * 66 + 2 * n + 1] = gi;
      float nr = wTr * gr - wTi * gi + tr;
      gi = wTr * gi + wTi * gr + ti;
      gr = nr;
    }
  }
  {
    size_t tb = (size_t)h * 4096;
#pragma unroll
    for (int e = 0; e < 2; e++) {
      int idx = e * 2048 + tid * 8;
      int r = idx >> 6, c = idx & 63;
      *(half8v*)(tab0 + r * 72 + c) = *(const half8v*)(Et + tb + idx);
      *(half8v*)(tab1 + r * 72 + c) = *(const half8v*)(Tt + tb + idx);
    }
  }
  __syncthreads();

  {
    int j = tid >> 3, m0 = (tid & 7) * 8;
    half8v g;
#pragma unroll
    for (int i = 0; i < 8; i++) g[i] = (half_t)SG[j * 66 + m0 + i];
    *(half8v*)(vg + j * 72 + m0) = g;
  }
  __syncthreads();

  // ---- Y phase: Y[j][r] = G~_j @ E' + u_j @ T' ; out = q*(Y + sD*u) ----
  acc[0] = (floatx4){0.f, 0.f, 0.f, 0.f};
  acc[1] = (floatx4){0.f, 0.f, 0.f, 0.f};
#pragma unroll
  for (int ks = 0; ks < 4; ks++) {
    int ko = ks * 16 + 4 * lg;
    half4v ag = *(const half4v*)(vg + (mi * 16 + lrow) * 72 + ko);
    half4v au = *(const half4v*)(uh + (mi * 16 + lrow) * 72 + ko);
#pragma unroll
    for (int tt = 0; tt < 2; tt++) {
      int ri = ri0 + tt * 2;
      half4v be = *(const half4v*)(tab0 + (ri * 16 + lrow) * 72 + ko);
      half4v bt = *(const half4v*)(tab1 + (ri * 16 + lrow) * 72 + ko);
      acc[tt] = __builtin_amdgcn_mfma_f32_16x16x16f16(ag, be, acc[tt], 0, 0, 0);
      acc[tt] = __builtin_amdgcn_mfma_f32_16x16x16f16(au, bt, acc[tt], 0, 0, 0);
    }
  }
  const half_t* qp = qbuf + (size_t)bh * 2048;
  float* op = outp + (size_t)bh * 2048;
#pragma unroll
  for (int tt = 0; tt < 2; tt++) {
    int ri = ri0 + tt * 2;
#pragma unroll
    for (int reg = 0; reg < 4; reg++) {
      int j = mi * 16 + 4 * lg + reg;
      int r = ri * 16 + lrow;
      int l = j * 64 + r;
      float y = acc[tt][reg] + sD4 * (float)uh[j * 72 + r];
      op[l] = (float)qp[l] * y;
    }
  }
}

// ---------------------------------------------------------------------------
extern "C" void kernel_launch(void* const* d_in, const int* in_sizes, int n_in,
                              void* d_out, int out_size, void* d_ws, size_t ws_size,
                              hipStream_t stream) {
  const float* x      = (const float*)d_in[0];
  const float* Wq     = (const float*)d_in[1];
  const float* bq     = (const float*)d_in[2];
  const float* Wk     = (const float*)d_in[3];
  const float* bk     = (const float*)d_in[4];
  const float* Wv     = (const float*)d_in[5];
  const float* bv     = (const float*)d_in[6];
  const float* shC    = (const float*)d_in[7];
  const float* shD    = (const float*)d_in[8];
  const float* log_dt = (const float*)d_in[9];
  const float* A_real = (const float*)d_in[10];
  const float* A_imag = (const float*)d_in[11];
  const float* C_re   = (const float*)d_in[12];
  const float* C_im   = (const float*)d_in[13];
  const float* s4D    = (const float*)d_in[14];
  float* out = (float*)d_out;
  half_t* wsh = (half_t*)d_ws;

  // ws layout (halfs): qbuf kbuf vbuf xT16 W16 Vt Et Tt T1t T2t | mc (f32)
  half_t* qbuf = wsh;                         // 8388608
  half_t* kbuf = wsh + 8388608;               // 8388608
  half_t* vbuf = wsh + 16777216;              // 8388608
  half_t* xT16 = wsh + 25165824;              // 8388608
  half_t* W16  = wsh + 33554432;              // 786432
  half_t* Vt   = wsh + 34340864;              // 2097152
  half_t* Et   = wsh + 36438016;              // 2097152
  half_t* Tt   = wsh + 38535168;              // 2097152
  half_t* T1t  = wsh + 40632320;              // 2097152
  half_t* T2t  = wsh + 42729472;              // 2097152
  float*  mc   = (float*)(wsh + 44826624);    // 131072 f32

  convert_w<<<3072, 256, 0, stream>>>(Wq, Wk, Wv, W16);
  transpose_x<<<dim3(64, 16, 8), dim3(32, 8), 0, stream>>>(x, xT16);
  s4d_setup<<<64, 256, 0, stream>>>(log_dt, A_real, A_imag, C_re, C_im, mc);
  s4d_tables<<<512, 256, 0, stream>>>(mc, shC, Vt, Et, Tt, T1t, T2t);
  gemm_qkv<<<dim3(1536), 256, 0, stream>>>(xT16, W16, bq, bk, bv,
                                           qbuf, kbuf, vbuf);
  s4d_main<<<4096, 256, 0, stream>>>(kbuf, vbuf, Vt, Et, Tt, T1t, T2t,
                                     mc, shD, s4D, qbuf, out);
}

// Round 4
// 96.532 us; speedup vs baseline: 2.7855x; 1.0461x over previous
//
#include <hip/hip_runtime.h>
#include <cstdint>

// ---------------------------------------------------------------------------
// H3 block: out = q * S4D( v * Shift(k) ),  q/k/v = W{q,k,v} @ x + b
// GEMM: merged M=1536 x N=16384 x K=512, BK=32 double-buffered prefetch,
//   global_load_lds(16B), slot-swizzled ds_read_b128, mfma_f32_16x16x32_f16.
// S4D + Shift as per-(b,h) chunked MFMA GEMMs (T=64) vs per-h tables stored
//   in pre-swizzled LDS-image layout (gload_lds staging, swizzled reads).
// Swizzle: within a 64-half row R, 16B slot s -> s ^ (R&7).
// ---------------------------------------------------------------------------

#define DMODEL 512
#define LSEQ 2048

typedef _Float16 half_t;
typedef __attribute__((ext_vector_type(4))) _Float16 half4v;
typedef __attribute__((ext_vector_type(8))) _Float16 half8v;
typedef __attribute__((ext_vector_type(4))) float floatx4;

#define SW(R, c) ((R) * 64 + ((((c) >> 3) ^ ((R) & 7)) << 3) + ((c) & 7))

__device__ __forceinline__ void gload_lds16(const half_t* g, half_t* l) {
  __builtin_amdgcn_global_load_lds(
      (const __attribute__((address_space(1))) uint32_t*)g,
      (__attribute__((address_space(3))) uint32_t*)l, 16, 0, 0);
}

// ---------------- convert W (3 x 512x512) fp32 -> f16 ----------------------
__global__ __launch_bounds__(256) void convert_w(
    const float* __restrict__ Wq, const float* __restrict__ Wk,
    const float* __restrict__ Wv, half_t* __restrict__ W16) {
  int i = blockIdx.x * 256 + threadIdx.x;
  const float* src = (i < 262144) ? Wq : ((i < 524288) ? Wk : Wv);
  int j = i & 262143;
  W16[i] = (half_t)src[j];
}

// ---------------- transpose x (B,D,L) f32 -> xT (B,L,D) f16 ----------------
__global__ __launch_bounds__(256) void transpose_x(
    const float* __restrict__ x, half_t* __restrict__ xT) {
  __shared__ float tile[32][33];
  int b = blockIdx.z;
  int d0 = blockIdx.y * 32;
  int l0 = blockIdx.x * 32;
  int tx = threadIdx.x, ty = threadIdx.y;       // 32 x 8
  const float* xp = x + (size_t)b * DMODEL * LSEQ;
#pragma unroll
  for (int k = 0; k < 4; k++)
    tile[ty + 8 * k][tx] = xp[(size_t)(d0 + ty + 8 * k) * LSEQ + l0 + tx];
  __syncthreads();
  half_t* op = xT + (size_t)b * LSEQ * DMODEL;
#pragma unroll
  for (int k = 0; k < 4; k++)
    op[(size_t)(l0 + ty + 8 * k) * DMODEL + d0 + tx] = (half_t)tile[tx][ty + 8 * k];
}

// ---------------- per-h table builder (setup folded in) --------------------
// Tables written in swizzled LDS-image layout (SW macro).
__global__ __launch_bounds__(256) void s4d_tables(
    const float* __restrict__ log_dt, const float* __restrict__ A_real,
    const float* __restrict__ A_imag, const float* __restrict__ C_re,
    const float* __restrict__ C_im, const float* __restrict__ shC,
    half_t* __restrict__ Vt, half_t* __restrict__ Et, half_t* __restrict__ Tt,
    half_t* __restrict__ T1t, half_t* __restrict__ T2t,
    float* __restrict__ wt2) {
  __shared__ float aL[32], bL[32], wrL[32], wiL[32], crL[32], ciL[32];
  __shared__ float Kt[64], tapl[64];
  int h = blockIdx.x;
  int tid = threadIdx.x;
  if (tid < 64) { Kt[tid] = 0.f; tapl[tid] = shC[h * 64 + tid]; }
  if (tid < 32) {
    int n = tid, hn = h * 32 + n;
    float dt = expf(log_dt[h]);
    float Ar = -expf(A_real[hn]), Ai = A_imag[hn];
    float a = dt * Ar, b = dt * Ai;
    float ea = expf(a);
    float wr = ea * cosf(b), wi = ea * sinf(b);
    float Am2 = Ar * Ar + Ai * Ai;
    float zr = wr - 1.0f, zi = wi;
    float qr = (zr * Ar + zi * Ai) / Am2;
    float qi = (zi * Ar - zr * Ai) / Am2;
    aL[n] = a; bL[n] = b; wrL[n] = wr; wiL[n] = wi;
    crL[n] = C_re[hn] * qr - C_im[hn] * qi;
    ciL[n] = C_re[hn] * qi + C_im[hn] * qr;
    float e64 = expf(64.0f * a);
    wt2[h * 64 + 2 * n]     = e64 * cosf(64.0f * b);
    wt2[h * 64 + 2 * n + 1] = e64 * sinf(64.0f * b);
  }
  __syncthreads();
  size_t base = (size_t)h * 4096;
  {
    int r = tid >> 2;
    int nb = (tid & 3) * 8;
    float ksum = 0.f;
#pragma unroll
    for (int i = 0; i < 8; i++) {
      int n = nb + i;
      float a = aL[n], b = bL[n];
      float cr = crL[n], ci = ciL[n];
      float er = expf(a * (float)r);
      float w0r = er * cosf(b * (float)r), w0i = er * sinf(b * (float)r);
      ksum += 2.f * (cr * w0r - ci * w0i);
      float wr = wrL[n], wi = wiL[n];
      float w1r = w0r * wr - w0i * wi, w1i = w0r * wi + w0i * wr;
      Et[base + SW(r, 2 * n)]     = (half_t)(2.f * (cr * w1r - ci * w1i));
      Et[base + SW(r, 2 * n + 1)] = (half_t)(-2.f * (cr * w1i + ci * w1r));
      Vt[base + SW(2 * n, 63 - r)]     = (half_t)w0r;
      Vt[base + SW(2 * n + 1, 63 - r)] = (half_t)w0i;
    }
    atomicAdd(&Kt[r], ksum);
  }
  __syncthreads();
#pragma unroll
  for (int e = 0; e < 16; e++) {
    int idx = e * 256 + tid;
    int r = idx >> 6, t = idx & 63;
    int d = r - t;
    size_t a = base + SW(r, t);
    Tt[a]  = (d >= 0) ? (half_t)Kt[d] : (half_t)0.f;
    T1t[a] = (d >= 0) ? (half_t)tapl[d] : (half_t)0.f;
    T2t[a] = (d < 0) ? (half_t)tapl[64 + d] : (half_t)0.f;
  }
}

// ---------------- merged qkv GEMM (BK=32, dbuf prefetch) -------------------
__global__ __launch_bounds__(256) void gemm_qkv(
    const half_t* __restrict__ xT, const half_t* __restrict__ Wstk,
    const float* __restrict__ bq, const float* __restrict__ bk,
    const float* __restrict__ bv, half_t* __restrict__ outq,
    half_t* __restrict__ outk, half_t* __restrict__ outv) {
  __shared__ half_t As[2][128 * 32];
  __shared__ half_t Bs[2][128 * 32];
  int flat = blockIdx.x;                         // 1536 = 8 xcd x 192
  int swz = (flat & 7) * 192 + (flat >> 3);
  int nt = swz / 12, mt = swz - nt * 12;
  int n0 = nt * 128, m0 = mt * 128;
  int tid = threadIdx.x;
  int lane = tid & 63, wid = tid >> 6;
  int wr = wid >> 1, wc = wid & 1;
  int lrow = lane & 15, lg = lane >> 4;          // frag row / k-slot (0..3)
  int r_in = lane >> 2, s_in = lane & 3;         // staging row/slot within chunk

  floatx4 acc[4][4];
#pragma unroll
  for (int i = 0; i < 4; i++)
#pragma unroll
    for (int j = 0; j < 4; j++) acc[i][j] = (floatx4){0.f, 0.f, 0.f, 0.f};

  auto STAGE = [&](int buf, int kk) {
#pragma unroll
    for (int i = 0; i < 2; i++) {
      int c = wid * 2 + i;                       // chunk: 16 rows x 32 halfs
      int row = c * 16 + r_in;
      int ss = s_in ^ ((row >> 1) & 3);          // inverse-swizzled source slot
      gload_lds16(Wstk + (size_t)(m0 + row) * 512 + kk + ss * 8,
                  &As[buf][c * 512]);
      gload_lds16(xT + (size_t)(n0 + row) * 512 + kk + ss * 8,
                  &Bs[buf][c * 512]);
    }
  };

  STAGE(0, 0);
  __syncthreads();
  int cur = 0;
  for (int t = 0; t < 16; t++) {
    if (t < 15) STAGE(cur ^ 1, (t + 1) * 32);    // prefetch flies during MFMA
    half8v af[4], bf[4];
#pragma unroll
    for (int i = 0; i < 4; i++) {
      int r = wr * 64 + i * 16 + lrow;
      af[i] = *(const half8v*)(&As[cur][r * 32 + (lg ^ ((r >> 1) & 3)) * 8]);
    }
#pragma unroll
    for (int j = 0; j < 4; j++) {
      int r = wc * 64 + j * 16 + lrow;
      bf[j] = *(const half8v*)(&Bs[cur][r * 32 + (lg ^ ((r >> 1) & 3)) * 8]);
    }
#pragma unroll
    for (int i = 0; i < 4; i++)
#pragma unroll
      for (int j = 0; j < 4; j++)
        acc[i][j] = __builtin_amdgcn_mfma_f32_16x16x32_f16(af[i], bf[j],
                                                           acc[i][j], 0, 0, 0);
    __syncthreads();                             // drains prefetch tail
    cur ^= 1;
  }

  // epilogue: D col = lane&15 (n), row = 4*(lane>>4)+reg (m)
  int z = m0 >> 9;                               // uniform per block
  const float* bias = (z == 0) ? bq : ((z == 1) ? bk : bv);
  half_t* outp = (z == 0) ? outq : ((z == 1) ? outk : outv);
#pragma unroll
  for (int i = 0; i < 4; i++) {
    int d = (m0 + wr * 64 + i * 16 + 4 * lg) & 511;
#pragma unroll
    for (int j = 0; j < 4; j++) {
      int n = n0 + wc * 64 + j * 16 + lrow;
      int b = n >> 11, l = n & 2047;
#pragma unroll
      for (int reg = 0; reg < 4; reg++) {
        float val = acc[i][j][reg] + bias[d + reg];
        size_t bhbase = ((size_t)(b * 512 + d + reg)) * 2048;
        if (z == 0) {
          outp[bhbase + l] = (half_t)val;        // q: linear (b,h,l)
        } else {                                  // k,v: swizzled LDS image
          int jj = l >> 6, c = l & 63;
          outp[bhbase + SW(jj, c)] = (half_t)val;
        }
      }
    }
  }
}

// ---------------- fused Shift + S4D + final q-multiply ---------------------
// One block per (b,h); wave w: mi = w&1 (chunk-tile), ri in {w>>1, w>>1+2}.
__global__ __launch_bounds__(256) void s4d_main(
    const half_t* __restrict__ kimg, const half_t* __restrict__ vimg,
    const half_t* __restrict__ T1t, const half_t* __restrict__ T2t,
    const half_t* __restrict__ Vt, const half_t* __restrict__ Et,
    const half_t* __restrict__ Tt, const float* __restrict__ wt2,
    const float* __restrict__ shD, const float* __restrict__ s4D,
    const half_t* __restrict__ qbuf, float* __restrict__ outp) {
  __shared__ half_t kl[33 * 64];   // row 0 zeros; row 1+j = k chunk j
  __shared__ half_t vg[32 * 64];   // v, later G~ (f16)
  __shared__ half_t uh[32 * 64];   // u = v * shift(k)
  __shared__ half_t tab0[64 * 64]; // T1 -> E
  __shared__ half_t tab1[64 * 64]; // T2 -> T
  __shared__ half_t tab2[64 * 64]; // V
  __shared__ float SG[32 * 66];
  int bh = blockIdx.x;
  int h = bh & 511;
  int tid = threadIdx.x;
  int lane = tid & 63, wid = tid >> 6;
  int lrow = lane & 15, lg = lane >> 4;
  int mi = wid & 1;
  int ri0 = wid >> 1;

  // ---- stage k, v, T1, T2, V via gload_lds (8 per wave) ----
  {
    const half_t* kp = kimg + (size_t)bh * 2048;
    const half_t* vp = vimg + (size_t)bh * 2048;
    size_t tb = (size_t)h * 4096;
    gload_lds16(kp + wid * 512 + lane * 8, kl + 64 + wid * 512);
    gload_lds16(vp + wid * 512 + lane * 8, vg + wid * 512);
#pragma unroll
    for (int i = 0; i < 2; i++) {
      int c = wid * 2 + i;
      gload_lds16(T1t + tb + c * 512 + lane * 8, tab0 + c * 512);
      gload_lds16(T2t + tb + c * 512 + lane * 8, tab1 + c * 512);
      gload_lds16(Vt + tb + c * 512 + lane * 8, tab2 + c * 512);
    }
  }
  if (tid < 8) {
    half8v zz = {(_Float16)0, (_Float16)0, (_Float16)0, (_Float16)0,
                 (_Float16)0, (_Float16)0, (_Float16)0, (_Float16)0};
    *(half8v*)(kl + tid * 8) = zz;
  }
  float sDsh = shD[h];
  float sD4 = s4D[h];
  __syncthreads();

  // frag read helper: row r in buffer, logical slot ks*4+lg, key
#define LDF(base, r, ks, key) \
  (*(const half8v*)((base) + (r) * 64 + (((ks) * 4 + lg) ^ (key)) * 8))

  floatx4 acc[2];
  // ---- shift: shift[j][r] = k_j @ T1' + k_{j-1} @ T2' ----
  acc[0] = (floatx4){0.f, 0.f, 0.f, 0.f};
  acc[1] = (floatx4){0.f, 0.f, 0.f, 0.f};
  {
    int jA = mi * 16 + lrow;
    int key1 = lrow & 7, key2 = (lrow + 7) & 7;
#pragma unroll
    for (int ks = 0; ks < 2; ks++) {
      half8v a1 = LDF(kl, 1 + jA, ks, key1);
      half8v a2 = LDF(kl, jA, ks, key2);
#pragma unroll
      for (int tt = 0; tt < 2; tt++) {
        int rb = (ri0 + tt * 2) * 16 + lrow;
        half8v b1 = LDF(tab0, rb, ks, lrow & 7);
        half8v b2 = LDF(tab1, rb, ks, lrow & 7);
        acc[tt] = __builtin_amdgcn_mfma_f32_16x16x32_f16(a1, b1, acc[tt], 0, 0, 0);
        acc[tt] = __builtin_amdgcn_mfma_f32_16x16x32_f16(a2, b2, acc[tt], 0, 0, 0);
      }
    }
  }
  // u = v * (shift + shD*k)
#pragma unroll
  for (int tt = 0; tt < 2; tt++) {
#pragma unroll
    for (int reg = 0; reg < 4; reg++) {
      int j = mi * 16 + 4 * lg + reg;
      int r = (ri0 + tt * 2) * 16 + lrow;
      int cph = (((r >> 3) ^ (j & 7)) << 3) + (r & 7);
      float kvv = (float)kl[(1 + j) * 64 + cph];
      float vvv = (float)vg[j * 64 + cph];
      uh[j * 64 + cph] = (half_t)(vvv * (acc[tt][reg] + sDsh * kvv));
    }
  }
  __syncthreads();

  // ---- issue E,T stage (overlaps with S phase) ----
  {
    size_t tb = (size_t)h * 4096;
#pragma unroll
    for (int i = 0; i < 2; i++) {
      int c = wid * 2 + i;
      gload_lds16(Et + tb + c * 512 + lane * 8, tab0 + c * 512);
      gload_lds16(Tt + tb + c * 512 + lane * 8, tab1 + c * 512);
    }
  }

  // ---- S phase: S[j][m] = u_j @ V' ----
  acc[0] = (floatx4){0.f, 0.f, 0.f, 0.f};
  acc[1] = (floatx4){0.f, 0.f, 0.f, 0.f};
#pragma unroll
  for (int ks = 0; ks < 2; ks++) {
    half8v a = LDF(uh, mi * 16 + lrow, ks, lrow & 7);
#pragma unroll
    for (int tt = 0; tt < 2; tt++) {
      int rb = (ri0 + tt * 2) * 16 + lrow;
      half8v b = LDF(tab2, rb, ks, lrow & 7);
      acc[tt] = __builtin_amdgcn_mfma_f32_16x16x32_f16(a, b, acc[tt], 0, 0, 0);
    }
  }
#pragma unroll
  for (int tt = 0; tt < 2; tt++) {
    int ri = ri0 + tt * 2;
#pragma unroll
    for (int reg = 0; reg < 4; reg++) {
      int j = mi * 16 + 4 * lg + reg;
      SG[j * 66 + ri * 16 + lrow] = acc[tt][reg];
    }
  }
  __syncthreads();   // drains E,T stage too

  // ---- scan over chunks (thread n), SG[j] <- G_{j-1} ----
  if (tid < 32) {
    int n = tid;
    float wTr = wt2[h * 64 + 2 * n], wTi = wt2[h * 64 + 2 * n + 1];
    float gr = 0.f, gi = 0.f;
    for (int j = 0; j < 32; j++) {
      float tr = SG[j * 66 + 2 * n], ti = SG[j * 66 + 2 * n + 1];
      SG[j * 66 + 2 * n] = gr; SG[j * 66 + 2 * n + 1] = gi;
      float nr = wTr * gr - wTi * gi + tr;
      gi = wTr * gi + wTi * gr + ti;
      gr = nr;
    }
  }
  __syncthreads();

  // ---- convert G (f32) -> f16 into vg (swizzled) ----
  {
    int j = tid >> 3, s = tid & 7;
    half8v g;
#pragma unroll
    for (int i = 0; i < 8; i++) g[i] = (half_t)SG[j * 66 + s * 8 + i];
    *(half8v*)(vg + j * 64 + (s ^ (j & 7)) * 8) = g;
  }
  __syncthreads();

  // ---- Y: Y[j][r] = G~_j @ E' + u_j @ T' ; out = q*(Y + sD*u) ----
  acc[0] = (floatx4){0.f, 0.f, 0.f, 0.f};
  acc[1] = (floatx4){0.f, 0.f, 0.f, 0.f};
#pragma unroll
  for (int ks = 0; ks < 2; ks++) {
    half8v ag = LDF(vg, mi * 16 + lrow, ks, lrow & 7);
    half8v au = LDF(uh, mi * 16 + lrow, ks, lrow & 7);
#pragma unroll
    for (int tt = 0; tt < 2; tt++) {
      int rb = (ri0 + tt * 2) * 16 + lrow;
      half8v be = LDF(tab0, rb, ks, lrow & 7);
      half8v bt = LDF(tab1, rb, ks, lrow & 7);
      acc[tt] = __builtin_amdgcn_mfma_f32_16x16x32_f16(ag, be, acc[tt], 0, 0, 0);
      acc[tt] = __builtin_amdgcn_mfma_f32_16x16x32_f16(au, bt, acc[tt], 0, 0, 0);
    }
  }
  const half_t* qp = qbuf + (size_t)bh * 2048;
  float* op = outp + (size_t)bh * 2048;
#pragma unroll
  for (int tt = 0; tt < 2; tt++) {
#pragma unroll
    for (int reg = 0; reg < 4; reg++) {
      int j = mi * 16 + 4 * lg + reg;
      int r = (ri0 + tt * 2) * 16 + lrow;
      int cph = (((r >> 3) ^ (j & 7)) << 3) + (r & 7);
      float y = acc[tt][reg] + sD4 * (float)uh[j * 64 + cph];
      int l = j * 64 + r;
      op[l] = (float)qp[l] * y;
    }
  }
#undef LDF
}

// ---------------------------------------------------------------------------
extern "C" void kernel_launch(void* const* d_in, const int* in_sizes, int n_in,
                              void* d_out, int out_size, void* d_ws, size_t ws_size,
                              hipStream_t stream) {
  const float* x      = (const float*)d_in[0];
  const float* Wq     = (const float*)d_in[1];
  const float* bq     = (const float*)d_in[2];
  const float* Wk     = (const float*)d_in[3];
  const float* bk     = (const float*)d_in[4];
  const float* Wv     = (const float*)d_in[5];
  const float* bv     = (const float*)d_in[6];
  const float* shC    = (const float*)d_in[7];
  const float* shD    = (const float*)d_in[8];
  const float* log_dt = (const float*)d_in[9];
  const float* A_real = (const float*)d_in[10];
  const float* A_imag = (const float*)d_in[11];
  const float* C_re   = (const float*)d_in[12];
  const float* C_im   = (const float*)d_in[13];
  const float* s4D    = (const float*)d_in[14];
  float* out = (float*)d_out;
  half_t* wsh = (half_t*)d_ws;

  half_t* qbuf = wsh;                         // 8388608 halfs (linear)
  half_t* kbuf = wsh + 8388608;               // 8388608 (swizzled image)
  half_t* vbuf = wsh + 16777216;              // 8388608 (swizzled image)
  half_t* xT16 = wsh + 25165824;              // 8388608
  half_t* W16  = wsh + 33554432;              // 786432
  half_t* Vt   = wsh + 34340864;              // 2097152 (swizzled image)
  half_t* Et   = wsh + 36438016;              // 2097152
  half_t* Tt   = wsh + 38535168;              // 2097152
  half_t* T1t  = wsh + 40632320;              // 2097152
  half_t* T2t  = wsh + 42729472;              // 2097152
  float*  wt2  = (float*)(wsh + 44826624);    // 32768 f32

  convert_w<<<3072, 256, 0, stream>>>(Wq, Wk, Wv, W16);
  transpose_x<<<dim3(64, 16, 8), dim3(32, 8), 0, stream>>>(x, xT16);
  s4d_tables<<<512, 256, 0, stream>>>(log_dt, A_real, A_imag, C_re, C_im, shC,
                                      Vt, Et, Tt, T1t, T2t, wt2);
  gemm_qkv<<<dim3(1536), 256, 0, stream>>>(xT16, W16, bq, bk, bv,
                                           qbuf, kbuf, vbuf);
  s4d_main<<<4096, 256, 0, stream>>>(kbuf, vbuf, T1t, T2t, Vt, Et, Tt,
                                     wt2, shD, s4D, qbuf, out);
}